// Round 1
// baseline (292.596 us; speedup 1.0000x reference)
//
#include <hip/hip_runtime.h>

#define N_NODES 3072
#define IN_DIM 512
#define OUT_DIM 64
#define HEADS 8
#define NEG_SLOPE 0.2f
#define MAX_E 1024

__device__ inline float waveMax(float v) {
#pragma unroll
    for (int o = 32; o > 0; o >>= 1) v = fmaxf(v, __shfl_down(v, o, 64));
    return v;
}
__device__ inline float waveSum(float v) {
#pragma unroll
    for (int o = 32; o > 0; o >>= 1) v += __shfl_down(v, o, 64);
    return v;
}

// Kernel 1: per-head projection h[h,n,:] = x[n,:] @ W[h,:,:], plus fused
// f_src[h,n] = h . a_src[h], f_dst[h,n] = h . a_dst[h].
// One 64-lane wave per (head, n) pair; lane = output dim o.
__global__ __launch_bounds__(256) void gat_proj(
    const float* __restrict__ x, const float* __restrict__ W,
    const float* __restrict__ a_src, const float* __restrict__ a_dst,
    float* __restrict__ hbuf, float* __restrict__ fsrc, float* __restrict__ fdst) {
    int gid = blockIdx.x * 4 + (threadIdx.x >> 6);   // (head, n) pair index
    int o = threadIdx.x & 63;
    int head = gid / N_NODES;
    int n = gid - head * N_NODES;

    const float* xrow = x + (size_t)n * IN_DIM;
    const float* Wp = W + (size_t)head * IN_DIM * OUT_DIM + o;

    float acc = 0.f;
    for (int i0 = 0; i0 < IN_DIM; i0 += 64) {
        float xv = xrow[i0 + o];          // coalesced 256B load of x chunk
#pragma unroll
        for (int k = 0; k < 64; ++k) {
            acc = fmaf(__shfl(xv, k, 64), Wp[(i0 + k) * OUT_DIM], acc);
        }
    }
    hbuf[((size_t)head * N_NODES + n) * OUT_DIM + o] = acc;

    float ps = acc * a_src[head * OUT_DIM + o];
    float pd = acc * a_dst[head * OUT_DIM + o];
#pragma unroll
    for (int off = 32; off > 0; off >>= 1) {
        ps += __shfl_down(ps, off, 64);
        pd += __shfl_down(pd, off, 64);
    }
    if (o == 0) {
        fsrc[head * N_NODES + n] = ps;
        fdst[head * N_NODES + n] = pd;
    }
}

// Kernel 2: one block per destination row i. Compact adjacency row to an LDS
// edge list, then per head: masked softmax over edges only (non-edges
// contribute exp(-1e9 - m) == 0 exactly in fp32), gather-aggregate h[j,:].
__global__ __launch_bounds__(256) void gat_agg(
    const float* __restrict__ adj, const float* __restrict__ hbuf,
    const float* __restrict__ fsrc, const float* __restrict__ fdst,
    float* __restrict__ out) {
    __shared__ int s_idx[MAX_E];
    __shared__ float s_p[MAX_E];
    __shared__ float s_acc[256];
    __shared__ float s_red[4];
    __shared__ int s_cnt;

    int i = blockIdx.x;
    int t = threadIdx.x;
    if (t == 0) s_cnt = 0;
    __syncthreads();

    const float* arow = adj + (size_t)i * N_NODES;
    for (int j = t; j < N_NODES; j += 256) {
        if (arow[j] > 0.f) {
            int slot = atomicAdd(&s_cnt, 1);
            if (slot < MAX_E) s_idx[slot] = j;
        }
    }
    __syncthreads();
    int E = min(s_cnt, MAX_E);   // every row has self-loop -> E >= 1

    for (int head = 0; head < HEADS; ++head) {
        float fi = fsrc[head * N_NODES + i];

        // logits + max
        float m = -1e30f;
        for (int k = t; k < E; k += 256) {
            float e = fi + fdst[head * N_NODES + s_idx[k]];
            e = e > 0.f ? e : NEG_SLOPE * e;   // leaky relu
            s_p[k] = e;
            m = fmaxf(m, e);
        }
        float wm = waveMax(m);
        if ((t & 63) == 0) s_red[t >> 6] = wm;
        __syncthreads();
        float M = fmaxf(fmaxf(s_red[0], s_red[1]), fmaxf(s_red[2], s_red[3]));
        __syncthreads();   // before s_red reuse

        // exp + sum
        float ls = 0.f;
        for (int k = t; k < E; k += 256) {
            float p = __expf(s_p[k] - M);
            s_p[k] = p;
            ls += p;
        }
        float wsum = waveSum(ls);
        if ((t & 63) == 0) s_red[t >> 6] = wsum;
        __syncthreads();
        float L = s_red[0] + s_red[1] + s_red[2] + s_red[3];
        float inv = 1.f / L;

        // aggregate: lane o accumulates output dim o over a slice of edges
        int o = t & 63, sl = t >> 6;
        float acc = 0.f;
        for (int k = sl; k < E; k += 4) {
            acc = fmaf(s_p[k],
                       hbuf[((size_t)head * N_NODES + s_idx[k]) * OUT_DIM + o],
                       acc);
        }
        s_acc[t] = acc;
        __syncthreads();
        if (t < 64) {
            float r = (s_acc[t] + s_acc[t + 64]) + (s_acc[t + 128] + s_acc[t + 192]);
            out[(size_t)i * (HEADS * OUT_DIM) + head * OUT_DIM + t] = r * inv;
        }
        __syncthreads();
    }
}

extern "C" void kernel_launch(void* const* d_in, const int* in_sizes, int n_in,
                              void* d_out, int out_size, void* d_ws, size_t ws_size,
                              hipStream_t stream) {
    const float* x     = (const float*)d_in[0];
    const float* adj   = (const float*)d_in[1];
    const float* W     = (const float*)d_in[2];
    const float* a_src = (const float*)d_in[3];
    const float* a_dst = (const float*)d_in[4];
    float* out = (float*)d_out;

    float* hbuf = (float*)d_ws;                               // [H, N, OUT] = 6.29 MB
    float* fsrc = hbuf + (size_t)HEADS * N_NODES * OUT_DIM;   // [H, N]
    float* fdst = fsrc + HEADS * N_NODES;                     // [H, N]

    gat_proj<<<(HEADS * N_NODES) / 4, 256, 0, stream>>>(x, W, a_src, a_dst,
                                                        hbuf, fsrc, fdst);
    gat_agg<<<N_NODES, 256, 0, stream>>>(adj, hbuf, fsrc, fdst, out);
}

// Round 2
// 128.954 us; speedup vs baseline: 2.2690x; 2.2690x over previous
//
#include <hip/hip_runtime.h>

#define N_NODES 3072
#define IN_DIM 512
#define OUT_DIM 64
#define HEADS 8
#define NEG_SLOPE 0.2f
#define MAX_E 256

#define MT 32           // M-tile (nodes per block)
#define KT 32           // K-tile
#define AS_LD 40        // padded LDS leading dims (x40 bf16 = 80 B, 16B-aligned rows)
#define BS_LD 40

typedef __attribute__((ext_vector_type(8))) short bf16x8;
typedef __attribute__((ext_vector_type(4))) float f32x4;

__device__ inline unsigned short f2bf(float f) {   // RNE float->bf16
    union { float f; unsigned u; } v; v.f = f;
    unsigned r = (v.u + 0x7FFF + ((v.u >> 16) & 1)) >> 16;
    return (unsigned short)r;
}

__device__ inline float waveAllMax(float v) {
#pragma unroll
    for (int o = 32; o; o >>= 1) v = fmaxf(v, __shfl_xor(v, o, 64));
    return v;
}
__device__ inline float waveAllSum(float v) {
#pragma unroll
    for (int o = 32; o; o >>= 1) v += __shfl_xor(v, o, 64);
    return v;
}

// Kernel 1: h[head] = x @ W[head] via bf16 MFMA; fused f_src/f_dst.
// Block: 256 threads = 4 waves; computes a 32(M) x 64(N) tile for one head.
// Wave w: row-tile (w&1), col-tiles (w>>1)*2 .. +2. K-loop: 512/32 = 16 steps.
__global__ __launch_bounds__(256) void gat_proj(
    const float* __restrict__ x, const float* __restrict__ W,
    const float* __restrict__ a_src, const float* __restrict__ a_dst,
    float* __restrict__ hbuf, float* __restrict__ fsrc, float* __restrict__ fdst) {
    __shared__ unsigned short As[MT][AS_LD];           // A tile [m][k], bf16
    __shared__ unsigned short Bs[OUT_DIM][BS_LD];      // B tile transposed [n][k], bf16
    __shared__ float hs[MT][OUT_DIM + 1];              // h tile for f-pass

    const int t = threadIdx.x;
    const int head = blockIdx.y;
    const int m0 = blockIdx.x * MT;
    const int lane = t & 63;
    const int w = t >> 6;
    const int rt = w & 1;
    const int ct0 = (w >> 1) * 2;

    const float* Wh = W + (size_t)head * IN_DIM * OUT_DIM;

    f32x4 acc0 = {0.f, 0.f, 0.f, 0.f};
    f32x4 acc1 = {0.f, 0.f, 0.f, 0.f};

    const int arow = t >> 3;           // 0..31
    const int acol = (t & 7) * 4;      // 0..28
    const int bk   = t >> 3;           // 0..31
    const int bn0  = (t & 7) * 8;      // 0..56

    for (int ks = 0; ks < IN_DIM; ks += KT) {
        __syncthreads();
        // stage A: x[m0+arow][ks+acol .. +4]
        float4 av = *(const float4*)(x + (size_t)(m0 + arow) * IN_DIM + ks + acol);
        As[arow][acol + 0] = f2bf(av.x);
        As[arow][acol + 1] = f2bf(av.y);
        As[arow][acol + 2] = f2bf(av.z);
        As[arow][acol + 3] = f2bf(av.w);
        // stage B transposed: W[ks+bk][bn0 .. +8] -> Bs[n][k]
        const float* wp = Wh + (size_t)(ks + bk) * OUT_DIM + bn0;
        float4 b0 = *(const float4*)(wp);
        float4 b1 = *(const float4*)(wp + 4);
        Bs[bn0 + 0][bk] = f2bf(b0.x);
        Bs[bn0 + 1][bk] = f2bf(b0.y);
        Bs[bn0 + 2][bk] = f2bf(b0.z);
        Bs[bn0 + 3][bk] = f2bf(b0.w);
        Bs[bn0 + 4][bk] = f2bf(b1.x);
        Bs[bn0 + 5][bk] = f2bf(b1.y);
        Bs[bn0 + 6][bk] = f2bf(b1.z);
        Bs[bn0 + 7][bk] = f2bf(b1.w);
        __syncthreads();

        // A-frag: A[m=lane&15][k=q*8+j]; B-frag: B[k=q*8+j][n=lane&15]
        const int q = lane >> 4;
        bf16x8 afrag  = *(const bf16x8*)&As[(lane & 15) + rt * 16][q * 8];
        bf16x8 bfrag0 = *(const bf16x8*)&Bs[(lane & 15) + ct0 * 16][q * 8];
        bf16x8 bfrag1 = *(const bf16x8*)&Bs[(lane & 15) + (ct0 + 1) * 16][q * 8];
        acc0 = __builtin_amdgcn_mfma_f32_16x16x32_bf16(afrag, bfrag0, acc0, 0, 0, 0);
        acc1 = __builtin_amdgcn_mfma_f32_16x16x32_bf16(afrag, bfrag1, acc1, 0, 0, 0);
    }

    // epilogue: D-frag mapping col=lane&15, row=(lane>>4)*4+reg
    {
        const int col0 = ct0 * 16 + (lane & 15);
        const int row_b = rt * 16 + (lane >> 4) * 4;
#pragma unroll
        for (int i = 0; i < 4; ++i) {
            const int r = row_b + i;
            hs[r][col0] = acc0[i];
            hs[r][col0 + 16] = acc1[i];
            float* gp = hbuf + ((size_t)head * N_NODES + m0 + r) * OUT_DIM;
            gp[col0] = acc0[i];
            gp[col0 + 16] = acc1[i];
        }
    }
    __syncthreads();

    // f-pass: threads 0..127 -> f_src, 128..255 -> f_dst
    {
        const float* av = (t < 128 ? a_src : a_dst) + head * OUT_DIM;
        const int tt = t & 127;
        const int row = tt >> 2, part = tt & 3;
        float s = 0.f;
#pragma unroll
        for (int n = 0; n < 16; ++n) s += hs[row][part * 16 + n] * av[part * 16 + n];
        s += __shfl_xor(s, 1, 64);
        s += __shfl_xor(s, 2, 64);
        if (part == 0) {
            float* dst = (t < 128 ? fsrc : fdst);
            dst[head * N_NODES + m0 + row] = s;
        }
    }
}

// Kernel 2: one block per row i. Compact edge list once (float4 scan), then
// wave w handles heads w and w+4 independently (no block barriers after
// compaction). Non-edges excluded entirely (exp(-1e9-m)==0 in fp32).
__global__ __launch_bounds__(256) void gat_agg(
    const float* __restrict__ adj, const float* __restrict__ hbuf,
    const float* __restrict__ fsrc, const float* __restrict__ fdst,
    float* __restrict__ out) {
    __shared__ int s_idx[MAX_E];
    __shared__ float s_p[4][MAX_E];
    __shared__ int s_cnt;

    const int i = blockIdx.x;
    const int t = threadIdx.x;
    if (t == 0) s_cnt = 0;
    __syncthreads();

    const float4* arow4 = (const float4*)(adj + (size_t)i * N_NODES);
#pragma unroll
    for (int it = 0; it < 3; ++it) {
        const int jj = t + it * 256;           // 3*256 = 768 float4 = 3072
        float4 v = arow4[jj];
        const int j = jj * 4;
        if (v.x > 0.f) { int s = atomicAdd(&s_cnt, 1); if (s < MAX_E) s_idx[s] = j; }
        if (v.y > 0.f) { int s = atomicAdd(&s_cnt, 1); if (s < MAX_E) s_idx[s] = j + 1; }
        if (v.z > 0.f) { int s = atomicAdd(&s_cnt, 1); if (s < MAX_E) s_idx[s] = j + 2; }
        if (v.w > 0.f) { int s = atomicAdd(&s_cnt, 1); if (s < MAX_E) s_idx[s] = j + 3; }
    }
    __syncthreads();
    const int E = min(s_cnt, MAX_E);           // self-loop guarantees E >= 1
    const int w = t >> 6;
    const int lane = t & 63;

    for (int head = w; head < HEADS; head += 4) {
        const float fi = fsrc[head * N_NODES + i];

        // pass 1: logits + max
        float m = -1e30f;
        for (int k = lane; k < E; k += 64) {
            float e = fi + fdst[head * N_NODES + s_idx[k]];
            e = e > 0.f ? e : NEG_SLOPE * e;
            s_p[w][k] = e;
            m = fmaxf(m, e);
        }
        m = waveAllMax(m);

        // pass 2: exp + sum
        float sum = 0.f;
        for (int k = lane; k < E; k += 64) {
            float p = __expf(s_p[w][k] - m);
            s_p[w][k] = p;
            sum += p;
        }
        sum = waveAllSum(sum);
        const float inv = 1.f / sum;

        // aggregate: lane = output dim o; p and j broadcast from LDS
        float acc = 0.f;
#pragma unroll 4
        for (int k = 0; k < E; ++k) {
            acc = fmaf(s_p[w][k],
                       hbuf[((size_t)head * N_NODES + s_idx[k]) * OUT_DIM + lane],
                       acc);
        }
        out[(size_t)i * (HEADS * OUT_DIM) + head * OUT_DIM + lane] = acc * inv;
    }
}

extern "C" void kernel_launch(void* const* d_in, const int* in_sizes, int n_in,
                              void* d_out, int out_size, void* d_ws, size_t ws_size,
                              hipStream_t stream) {
    const float* x     = (const float*)d_in[0];
    const float* adj   = (const float*)d_in[1];
    const float* W     = (const float*)d_in[2];
    const float* a_src = (const float*)d_in[3];
    const float* a_dst = (const float*)d_in[4];
    float* out = (float*)d_out;

    float* hbuf = (float*)d_ws;                               // [H, N, OUT]
    float* fsrc = hbuf + (size_t)HEADS * N_NODES * OUT_DIM;   // [H, N]
    float* fdst = fsrc + HEADS * N_NODES;                     // [H, N]

    gat_proj<<<dim3(N_NODES / MT, HEADS), 256, 0, stream>>>(x, W, a_src, a_dst,
                                                            hbuf, fsrc, fdst);
    gat_agg<<<N_NODES, 256, 0, stream>>>(adj, hbuf, fsrc, fdst, out);
}

// Round 3
// 114.931 us; speedup vs baseline: 2.5458x; 1.1220x over previous
//
#include <hip/hip_runtime.h>

#define N_NODES 3072
#define IN_DIM 512
#define OUT_DIM 64
#define HEADS 8
#define NEG_SLOPE 0.2f
#define MAX_E 128            // Poisson(31.7) edges/row; 128 is >17 sigma

typedef __attribute__((ext_vector_type(8))) short bf16x8;
typedef __attribute__((ext_vector_type(4))) float f32x4;

#define XFRAG_TILES (N_NODES / 16)     // 192 row-tiles
#define KTILES (IN_DIM / 32)           // 16 k-tiles
#define XFRAG_THREADS (XFRAG_TILES * KTILES * 64)   // 196608
#define WFRAG_THREADS (HEADS * KTILES * 4 * 64)     // 32768

__device__ inline unsigned short f2bf(float f) {   // RNE float->bf16
    union { float f; unsigned u; } v; v.f = f;
    unsigned r = (v.u + 0x7FFF + ((v.u >> 16) & 1)) >> 16;
    return (unsigned short)r;
}

__device__ inline float waveAllMax(float v) {
#pragma unroll
    for (int o = 32; o; o >>= 1) v = fmaxf(v, __shfl_xor(v, o, 64));
    return v;
}
__device__ inline float waveAllSum(float v) {
#pragma unroll
    for (int o = 32; o; o >>= 1) v += __shfl_xor(v, o, 64);
    return v;
}

// Kernel 0: build bf16 fragment-ready copies of x and W.
// xfrag[rt][kt][lane][8]: lane l holds x[rt*16 + (l&15)][kt*32 + (l>>4)*8 + j]
// wfrag[head][kt][c][lane][8]: lane l holds W[head][kt*32+(l>>4)*8+j][c*16+(l&15)]
__global__ __launch_bounds__(256) void gat_prep(
    const float* __restrict__ x, const float* __restrict__ W,
    short* __restrict__ xfrag, short* __restrict__ wfrag) {
    int tid = blockIdx.x * 256 + threadIdx.x;
    if (tid < XFRAG_THREADS) {
        int lane = tid & 63;
        int kt = (tid >> 6) & (KTILES - 1);
        int rt = tid >> 10;
        int m = rt * 16 + (lane & 15);
        int k0 = kt * 32 + (lane >> 4) * 8;
        const float4* xp = (const float4*)(x + (size_t)m * IN_DIM + k0);
        float4 v0 = xp[0], v1 = xp[1];
        bf16x8 r;
        r[0] = (short)f2bf(v0.x); r[1] = (short)f2bf(v0.y);
        r[2] = (short)f2bf(v0.z); r[3] = (short)f2bf(v0.w);
        r[4] = (short)f2bf(v1.x); r[5] = (short)f2bf(v1.y);
        r[6] = (short)f2bf(v1.z); r[7] = (short)f2bf(v1.w);
        ((bf16x8*)xfrag)[tid] = r;
    } else {
        int t2 = tid - XFRAG_THREADS;
        if (t2 >= WFRAG_THREADS) return;
        int lane = t2 & 63;
        int c = (t2 >> 6) & 3;
        int kt = (t2 >> 8) & (KTILES - 1);
        int head = t2 >> 12;
        int n = c * 16 + (lane & 15);
        int k0 = kt * 32 + (lane >> 4) * 8;
        const float* wp = W + ((size_t)head * IN_DIM + k0) * OUT_DIM + n;
        bf16x8 r;
#pragma unroll
        for (int j = 0; j < 8; ++j) r[j] = (short)f2bf(wp[(size_t)j * OUT_DIM]);
        ((bf16x8*)wfrag)[t2] = r;
    }
}

// Kernel 1: h[head] = x @ W[head] via direct-fragment MFMA (no LDS staging,
// no barriers in main loop). Block = 4 waves = 32 rows x 64 cols, one head.
// Wave w owns col-tile w (16 cols), two 16-row A-frags.
__global__ __launch_bounds__(256) void gat_proj(
    const short* __restrict__ xfrag, const short* __restrict__ wfrag,
    const float* __restrict__ a_src, const float* __restrict__ a_dst,
    float* __restrict__ hbuf, float* __restrict__ fsrc, float* __restrict__ fdst) {
    __shared__ float hs[32][OUT_DIM + 1];

    const int t = threadIdx.x;
    const int lane = t & 63;
    const int w = t >> 6;
    const int head = blockIdx.y;
    const int m0 = blockIdx.x * 32;
    const int rt0 = blockIdx.x * 2;

    const bf16x8* xa = (const bf16x8*)xfrag + (size_t)rt0 * 16 * 64 + lane;
    const bf16x8* wb = (const bf16x8*)wfrag + ((size_t)head * KTILES * 4 + w) * 64 + lane;

    f32x4 acc0 = {0.f, 0.f, 0.f, 0.f};
    f32x4 acc1 = {0.f, 0.f, 0.f, 0.f};
#pragma unroll
    for (int kt = 0; kt < KTILES; ++kt) {
        bf16x8 a0 = xa[kt * 64];            // rows m0..m0+15
        bf16x8 a1 = xa[(16 + kt) * 64];     // rows m0+16..m0+31
        bf16x8 b  = wb[kt * 4 * 64];        // cols w*16..w*16+15
        acc0 = __builtin_amdgcn_mfma_f32_16x16x32_bf16(a0, b, acc0, 0, 0, 0);
        acc1 = __builtin_amdgcn_mfma_f32_16x16x32_bf16(a1, b, acc1, 0, 0, 0);
    }

    // D mapping: col=lane&15 (within tile), row=(lane>>4)*4+i
    const int col = w * 16 + (lane & 15);
    const int r0 = (lane >> 4) * 4;
    float* gp = hbuf + ((size_t)head * N_NODES + m0) * OUT_DIM;
#pragma unroll
    for (int i2 = 0; i2 < 4; ++i2) {
        hs[r0 + i2][col] = acc0[i2];
        hs[r0 + 16 + i2][col] = acc1[i2];
        gp[(size_t)(r0 + i2) * OUT_DIM + col] = acc0[i2];
        gp[(size_t)(r0 + 16 + i2) * OUT_DIM + col] = acc1[i2];
    }
    __syncthreads();

    // f-pass: threads 0..127 -> f_src, 128..255 -> f_dst
    {
        const float* av = (t < 128 ? a_src : a_dst) + head * OUT_DIM;
        const int tt = t & 127;
        const int row = tt >> 2, part = tt & 3;
        float s = 0.f;
#pragma unroll
        for (int n = 0; n < 16; ++n) s += hs[row][part * 16 + n] * av[part * 16 + n];
        s += __shfl_xor(s, 1, 64);
        s += __shfl_xor(s, 2, 64);
        if (part == 0) {
            float* dst = (t < 128 ? fsrc : fdst);
            dst[head * N_NODES + m0 + row] = s;
        }
    }
}

// Kernel 2: one block per row i. Compact edge list, then wave w handles heads
// {w, w+4} with interleaved (independent) load chains. p+idx fused into one
// ds_read_b64 broadcast per edge in the gather.
__global__ __launch_bounds__(256) void gat_agg(
    const float* __restrict__ adj, const float* __restrict__ hbuf,
    const float* __restrict__ fsrc, const float* __restrict__ fdst,
    float* __restrict__ out) {
    __shared__ int s_idx[MAX_E];
    __shared__ float s_pe[4][2][2 * MAX_E];
    __shared__ int s_cnt;

    const int i = blockIdx.x;
    const int t = threadIdx.x;
    if (t == 0) s_cnt = 0;
    __syncthreads();

    const float4* arow4 = (const float4*)(adj + (size_t)i * N_NODES);
#pragma unroll
    for (int it = 0; it < 3; ++it) {
        const int jj = t + it * 256;            // 768 float4 = 3072 cols
        float4 v = arow4[jj];
        const int j = jj * 4;
        if (v.x > 0.f) { int s = atomicAdd(&s_cnt, 1); if (s < MAX_E) s_idx[s] = j; }
        if (v.y > 0.f) { int s = atomicAdd(&s_cnt, 1); if (s < MAX_E) s_idx[s] = j + 1; }
        if (v.z > 0.f) { int s = atomicAdd(&s_cnt, 1); if (s < MAX_E) s_idx[s] = j + 2; }
        if (v.w > 0.f) { int s = atomicAdd(&s_cnt, 1); if (s < MAX_E) s_idx[s] = j + 3; }
    }
    __syncthreads();
    const int E = min(s_cnt, MAX_E);            // self-loop -> E >= 1
    const int w = t >> 6;
    const int lane = t & 63;
    const int h0 = w, h1 = w + 4;

    const float fiA = fsrc[h0 * N_NODES + i];
    const float fiB = fsrc[h1 * N_NODES + i];

    // pass 1: logits + max (both heads)
    float mA = -1e30f, mB = -1e30f;
    for (int k = lane; k < E; k += 64) {
        int j = s_idx[k];
        float eA = fiA + fdst[h0 * N_NODES + j];
        float eB = fiB + fdst[h1 * N_NODES + j];
        eA = eA > 0.f ? eA : NEG_SLOPE * eA;
        eB = eB > 0.f ? eB : NEG_SLOPE * eB;
        s_pe[w][0][2 * k] = eA; s_pe[w][0][2 * k + 1] = __int_as_float(j);
        s_pe[w][1][2 * k] = eB; s_pe[w][1][2 * k + 1] = __int_as_float(j);
        mA = fmaxf(mA, eA); mB = fmaxf(mB, eB);
    }
    mA = waveAllMax(mA); mB = waveAllMax(mB);

    // pass 2: exp + sum
    float sA = 0.f, sB = 0.f;
    for (int k = lane; k < E; k += 64) {
        float pA = __expf(s_pe[w][0][2 * k] - mA); s_pe[w][0][2 * k] = pA; sA += pA;
        float pB = __expf(s_pe[w][1][2 * k] - mB); s_pe[w][1][2 * k] = pB; sB += pB;
    }
    sA = waveAllSum(sA); sB = waveAllSum(sB);
    const float invA = 1.f / sA, invB = 1.f / sB;

    // gather-aggregate: lane = output dim; one ds_read_b64 broadcast per
    // (head, edge); unroll 8 -> ~16 outstanding global loads
    float accA = 0.f, accB = 0.f;
#pragma unroll 8
    for (int k = 0; k < E; ++k) {
        float2 a = *(const float2*)&s_pe[w][0][2 * k];
        float2 b = *(const float2*)&s_pe[w][1][2 * k];
        int ja = __float_as_int(a.y), jb = __float_as_int(b.y);
        accA = fmaf(a.x, hbuf[((size_t)h0 * N_NODES + ja) * OUT_DIM + lane], accA);
        accB = fmaf(b.x, hbuf[((size_t)h1 * N_NODES + jb) * OUT_DIM + lane], accB);
    }
    out[(size_t)i * (HEADS * OUT_DIM) + h0 * OUT_DIM + lane] = accA * invA;
    out[(size_t)i * (HEADS * OUT_DIM) + h1 * OUT_DIM + lane] = accB * invB;
}

extern "C" void kernel_launch(void* const* d_in, const int* in_sizes, int n_in,
                              void* d_out, int out_size, void* d_ws, size_t ws_size,
                              hipStream_t stream) {
    const float* x     = (const float*)d_in[0];
    const float* adj   = (const float*)d_in[1];
    const float* W     = (const float*)d_in[2];
    const float* a_src = (const float*)d_in[3];
    const float* a_dst = (const float*)d_in[4];
    float* out = (float*)d_out;

    float* hbuf = (float*)d_ws;                               // [H,N,64] fp32
    float* fsrc = hbuf + (size_t)HEADS * N_NODES * OUT_DIM;   // [H,N]
    float* fdst = fsrc + HEADS * N_NODES;                     // [H,N]
    short* xfrag = (short*)(fdst + HEADS * N_NODES);          // 192*16*64*8 bf16
    short* wfrag = xfrag + (size_t)XFRAG_TILES * KTILES * 64 * 8;

    gat_prep<<<(XFRAG_THREADS + WFRAG_THREADS) / 256, 256, 0, stream>>>(
        x, W, xfrag, wfrag);
    gat_proj<<<dim3(N_NODES / 32, HEADS), 256, 0, stream>>>(
        xfrag, wfrag, a_src, a_dst, hbuf, fsrc, fdst);
    gat_agg<<<N_NODES, 256, 0, stream>>>(adj, hbuf, fsrc, fdst, out);
}

// Round 4
// 107.870 us; speedup vs baseline: 2.7125x; 1.0655x over previous
//
#include <hip/hip_runtime.h>

#define N_NODES 3072
#define IN_DIM 512
#define OUT_DIM 64
#define HEADS 8
#define NEG_SLOPE 0.2f
#define MAX_E 128            // Poisson(~31) edges/row; 128 is >17 sigma

typedef __attribute__((ext_vector_type(8))) short bf16x8;
typedef __attribute__((ext_vector_type(4))) float f32x4;

#define XFRAG_TILES (N_NODES / 16)     // 192 row-tiles
#define KTILES (IN_DIM / 32)           // 16 k-tiles
#define XFRAG_THREADS (XFRAG_TILES * KTILES * 64)   // 196608
#define WFRAG_THREADS (HEADS * KTILES * 4 * 64)     // 32768

__device__ inline unsigned short f2bf(float f) {   // RNE float->bf16
    union { float f; unsigned u; } v; v.f = f;
    unsigned r = (v.u + 0x7FFF + ((v.u >> 16) & 1)) >> 16;
    return (unsigned short)r;
}

// Kernel 0: build bf16 fragment-ready copies of x and W.
// xfrag[rt][kt][lane][8]: lane l holds x[rt*16 + (l&15)][kt*32 + (l>>4)*8 + j]
// wfrag[head][kt][c][lane][8]: lane l holds W[head][kt*32+(l>>4)*8+j][c*16+(l&15)]
__global__ __launch_bounds__(256) void gat_prep(
    const float* __restrict__ x, const float* __restrict__ W,
    short* __restrict__ xfrag, short* __restrict__ wfrag) {
    int tid = blockIdx.x * 256 + threadIdx.x;
    if (tid < XFRAG_THREADS) {
        int lane = tid & 63;
        int kt = (tid >> 6) & (KTILES - 1);
        int rt = tid >> 10;
        int m = rt * 16 + (lane & 15);
        int k0 = kt * 32 + (lane >> 4) * 8;
        const float4* xp = (const float4*)(x + (size_t)m * IN_DIM + k0);
        float4 v0 = xp[0], v1 = xp[1];
        bf16x8 r;
        r[0] = (short)f2bf(v0.x); r[1] = (short)f2bf(v0.y);
        r[2] = (short)f2bf(v0.z); r[3] = (short)f2bf(v0.w);
        r[4] = (short)f2bf(v1.x); r[5] = (short)f2bf(v1.y);
        r[6] = (short)f2bf(v1.z); r[7] = (short)f2bf(v1.w);
        ((bf16x8*)xfrag)[tid] = r;
    } else {
        int t2 = tid - XFRAG_THREADS;
        if (t2 >= WFRAG_THREADS) return;
        int lane = t2 & 63;
        int c = (t2 >> 6) & 3;
        int kt = (t2 >> 8) & (KTILES - 1);
        int head = t2 >> 12;
        int n = c * 16 + (lane & 15);
        int k0 = kt * 32 + (lane >> 4) * 8;
        const float* wp = W + ((size_t)head * IN_DIM + k0) * OUT_DIM + n;
        bf16x8 r;
#pragma unroll
        for (int j = 0; j < 8; ++j) r[j] = (short)f2bf(wp[(size_t)j * OUT_DIM]);
        ((bf16x8*)wfrag)[t2] = r;
    }
}

// Kernel 1: h[head] = x @ W[head] via direct-fragment MFMA (no LDS staging,
// no barriers in main loop). Block = 4 waves = 32 rows x 64 cols, one head.
// Epilogue writes h as bf16 NODE-MAJOR: hb[n][head*64 + col] (L2-resident
// 3.1 MB buffer for the agg gather), plus fp32 f_src/f_dst via LDS tile.
__global__ __launch_bounds__(256) void gat_proj(
    const short* __restrict__ xfrag, const short* __restrict__ wfrag,
    const float* __restrict__ a_src, const float* __restrict__ a_dst,
    unsigned short* __restrict__ hb, float* __restrict__ fsrc, float* __restrict__ fdst) {
    __shared__ float hs[32][OUT_DIM + 1];

    const int t = threadIdx.x;
    const int lane = t & 63;
    const int w = t >> 6;
    const int head = blockIdx.y;
    const int m0 = blockIdx.x * 32;
    const int rt0 = blockIdx.x * 2;

    const bf16x8* xa = (const bf16x8*)xfrag + (size_t)rt0 * 16 * 64 + lane;
    const bf16x8* wb = (const bf16x8*)wfrag + ((size_t)head * KTILES * 4 + w) * 64 + lane;

    f32x4 acc0 = {0.f, 0.f, 0.f, 0.f};
    f32x4 acc1 = {0.f, 0.f, 0.f, 0.f};
#pragma unroll
    for (int kt = 0; kt < KTILES; ++kt) {
        bf16x8 a0 = xa[kt * 64];            // rows m0..m0+15
        bf16x8 a1 = xa[(16 + kt) * 64];     // rows m0+16..m0+31
        bf16x8 b  = wb[kt * 4 * 64];        // cols w*16..w*16+15
        acc0 = __builtin_amdgcn_mfma_f32_16x16x32_bf16(a0, b, acc0, 0, 0, 0);
        acc1 = __builtin_amdgcn_mfma_f32_16x16x32_bf16(a1, b, acc1, 0, 0, 0);
    }

    // D mapping: col=lane&15 (within tile), row=(lane>>4)*4+i
    const int col = w * 16 + (lane & 15);
    const int r0 = (lane >> 4) * 4;
    unsigned short* hp = hb + (size_t)m0 * (HEADS * OUT_DIM) + head * OUT_DIM + col;
#pragma unroll
    for (int i2 = 0; i2 < 4; ++i2) {
        hs[r0 + i2][col] = acc0[i2];
        hs[r0 + 16 + i2][col] = acc1[i2];
        hp[(size_t)(r0 + i2) * (HEADS * OUT_DIM)] = f2bf(acc0[i2]);
        hp[(size_t)(r0 + 16 + i2) * (HEADS * OUT_DIM)] = f2bf(acc1[i2]);
    }
    __syncthreads();

    // f-pass: threads 0..127 -> f_src, 128..255 -> f_dst (fp32 from LDS tile)
    {
        const float* av = (t < 128 ? a_src : a_dst) + head * OUT_DIM;
        const int tt = t & 127;
        const int row = tt >> 2, part = tt & 3;
        float s = 0.f;
#pragma unroll
        for (int n = 0; n < 16; ++n) s += hs[row][part * 16 + n] * av[part * 16 + n];
        s += __shfl_xor(s, 1, 64);
        s += __shfl_xor(s, 2, 64);
        if (part == 0) {
            float* dst = (t < 128 ? fsrc : fdst);
            dst[head * N_NODES + m0 + row] = s;
        }
    }
}

// Kernel 2: one block per row i. Compact edge list, then wave w handles heads
// {2w, 2w+1}: lanes 0..31 -> head 2w, lanes 32..63 -> head 2w+1, each lane
// owning 2 output dims. Gather = ONE coalesced 256B dword load per wave per
// edge (bf16 pairs, node-major hb), covering both heads. Half-wave softmax.
__global__ __launch_bounds__(256) void gat_agg(
    const float* __restrict__ adj, const unsigned short* __restrict__ hb,
    const float* __restrict__ fsrc, const float* __restrict__ fdst,
    float* __restrict__ out) {
    __shared__ int s_idx[MAX_E];
    __shared__ float s_p[HEADS][MAX_E];
    __shared__ int s_cnt;

    const int i = blockIdx.x;
    const int t = threadIdx.x;
    if (t == 0) s_cnt = 0;
    __syncthreads();

    const float4* arow4 = (const float4*)(adj + (size_t)i * N_NODES);
#pragma unroll
    for (int it = 0; it < 3; ++it) {
        const int jj = t + it * 256;            // 768 float4 = 3072 cols
        float4 v = arow4[jj];
        const int j = jj * 4;
        if (v.x > 0.f) { int s = atomicAdd(&s_cnt, 1); if (s < MAX_E) s_idx[s] = j; }
        if (v.y > 0.f) { int s = atomicAdd(&s_cnt, 1); if (s < MAX_E) s_idx[s] = j + 1; }
        if (v.z > 0.f) { int s = atomicAdd(&s_cnt, 1); if (s < MAX_E) s_idx[s] = j + 2; }
        if (v.w > 0.f) { int s = atomicAdd(&s_cnt, 1); if (s < MAX_E) s_idx[s] = j + 3; }
    }
    __syncthreads();
    const int E = min(s_cnt, MAX_E);            // self-loop -> E >= 1

    const int w = t >> 6;
    const int lane = t & 63;
    const int half = lane >> 5;                 // 0 or 1
    const int sl = lane & 31;                   // sub-lane within half
    const int head = 2 * w + half;

    const float fi = fsrc[head * N_NODES + i];

    // pass 1: logits + half-wave max
    float m = -1e30f;
    for (int k = sl; k < E; k += 32) {
        float e = fi + fdst[head * N_NODES + s_idx[k]];
        e = e > 0.f ? e : NEG_SLOPE * e;
        s_p[head][k] = e;
        m = fmaxf(m, e);
    }
#pragma unroll
    for (int o = 16; o; o >>= 1) m = fmaxf(m, __shfl_xor(m, o, 64));

    // pass 2: exp + half-wave sum
    float sum = 0.f;
    for (int k = sl; k < E; k += 32) {
        float p = __expf(s_p[head][k] - m);
        s_p[head][k] = p;
        sum += p;
    }
#pragma unroll
    for (int o = 16; o; o >>= 1) sum += __shfl_xor(sum, o, 64);
    const float inv = 1.f / sum;

    // gather-aggregate: lane owns dims {sl*2, sl*2+1} of its head.
    // One dword (bf16 pair) per lane per edge; wave covers 256B contiguous.
    const unsigned short* hbase = hb + head * OUT_DIM + sl * 2;
    float a0 = 0.f, a1 = 0.f;
#pragma unroll 8
    for (int k = 0; k < E; ++k) {
        const int j = s_idx[k];
        const float p = s_p[head][k];
        const unsigned u = *(const unsigned*)(hbase + (size_t)j * (HEADS * OUT_DIM));
        a0 = fmaf(p, __uint_as_float(u << 16), a0);
        a1 = fmaf(p, __uint_as_float(u & 0xffff0000u), a1);
    }
    float2 r = {a0 * inv, a1 * inv};
    *(float2*)(out + (size_t)i * (HEADS * OUT_DIM) + head * OUT_DIM + sl * 2) = r;
}

extern "C" void kernel_launch(void* const* d_in, const int* in_sizes, int n_in,
                              void* d_out, int out_size, void* d_ws, size_t ws_size,
                              hipStream_t stream) {
    const float* x     = (const float*)d_in[0];
    const float* adj   = (const float*)d_in[1];
    const float* W     = (const float*)d_in[2];
    const float* a_src = (const float*)d_in[3];
    const float* a_dst = (const float*)d_in[4];
    float* out = (float*)d_out;

    float* fsrc = (float*)d_ws;                               // [H,N]
    float* fdst = fsrc + HEADS * N_NODES;                     // [H,N]
    unsigned short* hb = (unsigned short*)(fdst + HEADS * N_NODES);   // [N, H*64] bf16
    short* xfrag = (short*)(hb + (size_t)N_NODES * HEADS * OUT_DIM);
    short* wfrag = xfrag + (size_t)XFRAG_TILES * KTILES * 64 * 8;

    gat_prep<<<(XFRAG_THREADS + WFRAG_THREADS) / 256, 256, 0, stream>>>(
        x, W, xfrag, wfrag);
    gat_proj<<<dim3(N_NODES / 32, HEADS), 256, 0, stream>>>(
        xfrag, wfrag, a_src, a_dst, hb, fsrc, fdst);
    gat_agg<<<N_NODES, 256, 0, stream>>>(adj, hb, fsrc, fdst, out);
}